// Round 1
// 203.471 us; speedup vs baseline: 1.0478x; 1.0478x over previous
//
#include <hip/hip_runtime.h>
#include <hip/hip_bf16.h>
#include <math.h>

typedef __hip_bfloat16 bf16;
typedef __bf16  bf16x8 __attribute__((ext_vector_type(8)));
typedef float   f32x4  __attribute__((ext_vector_type(4)));

#define BB 2
#define NN 2048
#define DD 1024
#define HH 16
#define HD 64
#define LOG2E   1.44269504f
#define SCALE_Q 0.18033688f   /* 0.125 * log2(e), folded into q */

// async global->LDS, 16B/lane; LDS dest = wave-uniform base + lane*16
__device__ __forceinline__ void glds16(const bf16* g, bf16* l) {
    __builtin_amdgcn_global_load_lds((const __attribute__((address_space(1))) void*)g,
                                     (__attribute__((address_space(3))) void*)l, 16, 0, 0);
}
__device__ __forceinline__ unsigned short bfu(float x) {
    bf16 b = __float2bfloat16(x);
    return __builtin_bit_cast(unsigned short, b);
}

// ---------------------------------------------------------------------------
// prep (single launch): [0,2048) cast x ; [2048,3072) bias_perm fp32 (8-wave
// consumption order) ; [3072,3840) transpose Wqkv ; [3840,4096) coordproj.
// ---------------------------------------------------------------------------
__global__ __launch_bounds__(256) void prep(const float* __restrict__ x,
                                            const float* __restrict__ bias,
                                            const float* __restrict__ W,
                                            const float* __restrict__ coords,
                                            const float* __restrict__ relw,
                                            bf16* __restrict__ xb,
                                            float* __restrict__ pbf,
                                            bf16* __restrict__ Wt,
                                            bf16* __restrict__ cpn) {
    __shared__ bf16 tsm[64][65];
    const int bid = blockIdx.x, tid = threadIdx.x;
    if (bid < 2048) {
        size_t i = ((size_t)bid * 256 + tid) * 8;
        float4 a = *(const float4*)(x + i);
        float4 b = *(const float4*)(x + i + 4);
        bf16 t[8];
        t[0] = __float2bfloat16(a.x); t[1] = __float2bfloat16(a.y);
        t[2] = __float2bfloat16(a.z); t[3] = __float2bfloat16(a.w);
        t[4] = __float2bfloat16(b.x); t[5] = __float2bfloat16(b.y);
        t[6] = __float2bfloat16(b.z); t[7] = __float2bfloat16(b.w);
        *(int4*)(xb + i) = *(int4*)t;
    } else if (bid < 3072) {
        // pbf[t*16 + g*4 + r] = log2e*bias[q][k], t = ((Qb*32+kt)*8+wave)*64+lane,
        // q = Qb*128 + wave*16 + quad*4 + r, k = kt*64 + g*16 + l15
        int t    = (bid - 2048) * 256 + tid;     // 0..262143
        int lane = t & 63;
        int wave = (t >> 6) & 7;
        int kt   = (t >> 9) & 31;
        int Qb   = t >> 14;
        int quad = lane >> 4, l15 = lane & 15;
        float v[16];
#pragma unroll
        for (int j = 0; j < 16; ++j) {
            int g = j >> 2, r = j & 3;
            int q = Qb * 128 + wave * 16 + quad * 4 + r;
            int k = kt * 64 + g * 16 + l15;
            v[j] = LOG2E * bias[(size_t)q * NN + k];
        }
        int4* dst = (int4*)(pbf + (size_t)t * 16);
#pragma unroll
        for (int i = 0; i < 4; ++i) dst[i] = ((int4*)v)[i];
    } else if (bid < 3840) {
        int idx = bid - 3072;                    // 0..767
        int n0 = (idx % 48) * 64;
        int k0 = (idx / 48) * 64;
        int tx = tid & 63, tg = tid >> 6;
#pragma unroll
        for (int i = 0; i < 16; ++i) {
            int r = tg + i * 4;
            tsm[r][tx] = __float2bfloat16(W[(size_t)(k0 + r) * 3072 + n0 + tx]);
        }
        __syncthreads();
#pragma unroll
        for (int i = 0; i < 16; ++i) {
            int r = tg + i * 4;
            Wt[(size_t)(n0 + r) * 1024 + k0 + tx] = tsm[tx][r];
        }
    } else {
        int idx = (bid - 3840) * 256 + tid;      // 0..65535
        int n  = idx & (NN - 1);
        int bh = idx >> 11;
        int h  = bh & (HH - 1);
        int b  = bh >> 4;
        float acc = 0.f;
#pragma unroll
        for (int c = 0; c < 3; ++c)
            acc += coords[(size_t)(b * NN + n) * 3 + c] * relw[h * 3 + c];
        cpn[idx] = __float2bfloat16(-LOG2E * acc);
    }
}

// ---------------------------------------------------------------------------
// qkv GEMM: 128x128 tile, BK=32, glds w=16, swizzle c^=((row>>1)&3).
// V written DIRECTLY TRANSPOSED (bh,d,n); q pre-scaled by SCALE_Q. (R6 kernel)
// ---------------------------------------------------------------------------
__global__ __launch_bounds__(256) void qkv_gemm(const bf16* __restrict__ X,
                                                const bf16* __restrict__ W,
                                                const float* __restrict__ bq,
                                                bf16* __restrict__ qo,
                                                bf16* __restrict__ ko,
                                                bf16* __restrict__ vt) {
    __shared__ __align__(16) bf16 As[128 * 32];
    __shared__ __align__(16) bf16 Bs[128 * 32];
    const int tid  = threadIdx.x;
    const int n0   = blockIdx.x * 128;
    const int m0   = blockIdx.y * 128;
    const int wave = tid >> 6, lane = tid & 63, l15 = lane & 15, quad = lane >> 4;
    const int wm   = wave >> 1, wn = wave & 1;

    f32x4 acc[4][4];
    const f32x4 z4 = {0.f, 0.f, 0.f, 0.f};
#pragma unroll
    for (int i = 0; i < 4; ++i)
#pragma unroll
        for (int j = 0; j < 4; ++j) acc[i][j] = z4;

    for (int kt = 0; kt < 1024; kt += 32) {
        __syncthreads();
#pragma unroll
        for (int j = 0; j < 2; ++j) {
            int s   = (wave * 2 + j) * 64 + lane;       // 0..511
            int row = s >> 2;                           // 0..127
            int c   = (s & 3) ^ ((row >> 1) & 3);       // swizzled col-block
            glds16(X + (size_t)(m0 + row) * 1024 + kt + c * 8, As + (wave * 2 + j) * 512);
            glds16(W + (size_t)(n0 + row) * 1024 + kt + c * 8, Bs + (wave * 2 + j) * 512);
        }
        __syncthreads();

        bf16x8 a[4], b[4];
#pragma unroll
        for (int mt = 0; mt < 4; ++mt) {
            int ra = wm * 64 + mt * 16 + l15;
            a[mt] = *(const bf16x8*)&As[ra * 32 + ((quad ^ ((ra >> 1) & 3)) * 8)];
        }
#pragma unroll
        for (int nt = 0; nt < 4; ++nt) {
            int rb = wn * 64 + nt * 16 + l15;
            b[nt] = *(const bf16x8*)&Bs[rb * 32 + ((quad ^ ((rb >> 1) & 3)) * 8)];
        }
#pragma unroll
        for (int mt = 0; mt < 4; ++mt)
#pragma unroll
            for (int nt = 0; nt < 4; ++nt)
                acc[mt][nt] = __builtin_amdgcn_mfma_f32_16x16x32_bf16(a[mt], b[nt], acc[mt][nt], 0, 0, 0);
    }

#pragma unroll
    for (int nt = 0; nt < 4; ++nt) {
        int c    = n0 + wn * 64 + nt * 16 + l15;   // 0..3071, tsel uniform per nt
        int tsel = c >> 10;
        int rem  = c & 1023;
        int h    = rem >> 6, d = rem & 63;
        float bias = bq[c];
        float qs   = (tsel == 0) ? SCALE_Q : 1.0f;
#pragma unroll
        for (int mt = 0; mt < 4; ++mt)
#pragma unroll
            for (int r = 0; r < 4; ++r) {
                int m = m0 + wm * 64 + mt * 16 + quad * 4 + r;   // 0..4095
                int b = m >> 11, n = m & (NN - 1);
                bf16 val = __float2bfloat16((acc[mt][nt][r] + bias) * qs);
                if (tsel == 2)
                    vt[((size_t)(b * HH + h) * HD + d) * NN + n] = val;
                else
                    ((tsel == 1) ? ko : qo)[((size_t)(b * HH + h) * NN + n) * HD + d] = val;
            }
    }
}

// ---------------------------------------------------------------------------
// flash attention v2: 512 threads = 8 waves x 16 q, 128 q/block, grid 512.
// Changes vs v1: (1) bias+cp folded into QK MFMA C-operand (removes 16 scalar
// adds/tile, bias latency off the critical chain); (2) bias register
// double-buffer prefetched one tile ahead; (3) f32x4 vector adds for C-init
// and l accumulation (v_pk_add_f32); (4) tile loop unrolled x2 so `cur` is a
// literal (LDS swizzle addresses become loop-invariant); (5) setprio around
// PV MFMA cluster. LDS 55296 B unchanged.
// ---------------------------------------------------------------------------
__global__ __launch_bounds__(512, 4) void attn(const bf16* __restrict__ Q,
                                               const bf16* __restrict__ K,
                                               const bf16* __restrict__ Vt_g,
                                               const bf16* __restrict__ cpn_g,
                                               const float* __restrict__ pbf,
                                               float* __restrict__ out) {
    __shared__ __align__(16) bf16 Ks[2][64 * 64];
    __shared__ __align__(16) bf16 Vs[2][64 * 64];      // [d][key]
    __shared__ __align__(16) unsigned PsW[8][16 * 36]; // packed P, per-wave
    __shared__ __align__(16) bf16 cpl[NN];             // -log2e * cp[bh][*]
    const int tid  = threadIdx.x;
    const int Qb   = blockIdx.x;           // 0..15
    const int bh   = blockIdx.y;           // 0..31
    const int b    = bh >> 4, h = bh & 15;
    const int q0   = Qb * 128;
    const int wave = tid >> 6, lane = tid & 63, l15 = lane & 15, quad = lane >> 4;
    const size_t base = (size_t)bh * NN * HD;

    // stage cp row (4 KB) with waves 0..3 (wave-uniform branch)
    if (wave < 4)
        glds16(cpn_g + bh * NN + (wave * 64 + lane) * 8, cpl + wave * 512);

    // Q fragments: 16 q-rows per wave, in registers for the whole kernel
    const int qrow = q0 + wave * 16 + l15;
    bf16x8 qf0 = *(const bf16x8*)&Q[base + (size_t)qrow * HD + quad * 8];
    bf16x8 qf1 = *(const bf16x8*)&Q[base + (size_t)qrow * HD + 32 + quad * 8];

    // hoisted staging geometry (one glds per buffer per wave)
    const int ps   = wave * 64 + lane;     // 0..511
    const int prow = ps >> 3;              // 0..63
    const int pcol = (ps & 7) ^ (prow & 7);

    // prologue: stage tile 0 into buffer 0
    glds16(K    + base + (size_t)prow * HD + pcol * 8, Ks[0] + wave * 512);
    glds16(Vt_g + base + (size_t)prow * NN + pcol * 8, Vs[0] + wave * 512);

    // bias: permuted fp32, register double-buffer. tile stride = 8192 floats.
    const float* bptr = pbf + ((((size_t)Qb * 32) * 8 + wave) * 64 + lane) * 16;
    float4 bvA[4], bvB[4];
#pragma unroll
    for (int i = 0; i < 4; ++i) bvA[i] = ((const float4*)bptr)[i];

    const f32x4 z4 = {0.f, 0.f, 0.f, 0.f};
    f32x4 l4 = z4;
    f32x4 o[4];
#pragma unroll
    for (int t = 0; t < 4; ++t) o[t] = z4;

#define ATTN_TILE(T, CUR, BVC, BVN)                                               \
    {                                                                             \
        __syncthreads();   /* buf[CUR] ready (vmcnt drained); buf[CUR^1] free */  \
        if ((T) < 31) {    /* prefetch K/V tile T+1 and bias T+1 */               \
            int kk1 = ((T) + 1) * 64;                                             \
            glds16(K    + base + (size_t)(kk1 + prow) * HD + pcol * 8,            \
                   Ks[(CUR) ^ 1] + wave * 512);                                   \
            glds16(Vt_g + base + (size_t)prow * NN + kk1 + pcol * 8,              \
                   Vs[(CUR) ^ 1] + wave * 512);                                   \
            const float* bp = bptr + (size_t)((T) + 1) * 8192;                    \
            BVN[0] = ((const float4*)bp)[0];                                      \
            BVN[1] = ((const float4*)bp)[1];                                      \
            BVN[2] = ((const float4*)bp)[2];                                      \
            BVN[3] = ((const float4*)bp)[3];                                      \
        }                                                                         \
        /* --- QK^T with C = bias' + mg (bias folded into MFMA accumulator) */    \
        f32x4 p4[4];                                                              \
        _Pragma("unroll")                                                         \
        for (int g = 0; g < 4; ++g) {                                             \
            float mgv = __bfloat162float(cpl[(T) * 64 + g * 16 + l15]);           \
            f32x4 mg4 = {mgv, mgv, mgv, mgv};                                     \
            f32x4 c0  = __builtin_bit_cast(f32x4, BVC[g]) + mg4;                  \
            int krow = g * 16 + l15, sw = krow & 7;                               \
            bf16x8 k0 = *(const bf16x8*)&Ks[(CUR)][krow * 64 + ((quad ^ sw) * 8)];         \
            bf16x8 k1 = *(const bf16x8*)&Ks[(CUR)][krow * 64 + (((4 + quad) ^ sw) * 8)];   \
            f32x4 s4 = __builtin_amdgcn_mfma_f32_16x16x32_bf16(qf0, k0, c0, 0, 0, 0);      \
            s4 = __builtin_amdgcn_mfma_f32_16x16x32_bf16(qf1, k1, s4, 0, 0, 0);   \
            f32x4 e;                                                              \
            e[0] = __builtin_amdgcn_exp2f(s4[0]);                                 \
            e[1] = __builtin_amdgcn_exp2f(s4[1]);                                 \
            e[2] = __builtin_amdgcn_exp2f(s4[2]);                                 \
            e[3] = __builtin_amdgcn_exp2f(s4[3]);                                 \
            p4[g] = e;                                                            \
            l4 = l4 + e;                                                          \
        }                                                                         \
        /* --- packed P write (8 b32), one wait, read back as A-frags */          \
        _Pragma("unroll")                                                         \
        for (int g2 = 0; g2 < 2; ++g2)                                            \
            _Pragma("unroll")                                                     \
            for (int r = 0; r < 4; ++r) {                                         \
                unsigned pk = (unsigned)bfu(p4[g2][r]) |                          \
                              ((unsigned)bfu(p4[g2 + 2][r]) << 16);               \
                PsW[wave][(quad * 4 + r) * 36 + g2 * 16 + l15] = pk;              \
            }                                                                     \
        asm volatile("s_waitcnt lgkmcnt(0)" ::: "memory");                        \
        const int4* pr = (const int4*)&PsW[wave][l15 * 36 + quad * 8];            \
        int4 da = pr[0], db = pr[1];                                              \
        union { unsigned u[4]; bf16x8 v; } u0, u1;                                \
        u0.u[0] = __builtin_amdgcn_perm(da.y, da.x, 0x05040100u);                 \
        u0.u[1] = __builtin_amdgcn_perm(da.w, da.z, 0x05040100u);                 \
        u0.u[2] = __builtin_amdgcn_perm(db.y, db.x, 0x05040100u);                 \
        u0.u[3] = __builtin_amdgcn_perm(db.w, db.z, 0x05040100u);                 \
        u1.u[0] = __builtin_amdgcn_perm(da.y, da.x, 0x07060302u);                 \
        u1.u[1] = __builtin_amdgcn_perm(da.w, da.z, 0x07060302u);                 \
        u1.u[2] = __builtin_amdgcn_perm(db.y, db.x, 0x07060302u);                 \
        u1.u[3] = __builtin_amdgcn_perm(db.w, db.z, 0x07060302u);                 \
        /* --- PV (V frags loaded at use) */                                      \
        __builtin_amdgcn_s_setprio(1);                                            \
        _Pragma("unroll")                                                         \
        for (int tt = 0; tt < 4; ++tt) {                                          \
            int drow = tt * 16 + l15, sw2 = drow & 7;                             \
            bf16x8 v0 = *(const bf16x8*)&Vs[(CUR)][drow * 64 + ((quad ^ sw2) * 8)];        \
            bf16x8 v1 = *(const bf16x8*)&Vs[(CUR)][drow * 64 + (((4 + quad) ^ sw2) * 8)];  \
            o[tt] = __builtin_amdgcn_mfma_f32_16x16x32_bf16(u0.v, v0, o[tt], 0, 0, 0);     \
            o[tt] = __builtin_amdgcn_mfma_f32_16x16x32_bf16(u1.v, v1, o[tt], 0, 0, 0);     \
        }                                                                         \
        __builtin_amdgcn_s_setprio(0);                                            \
    }

    for (int t = 0; t < 32; t += 2) {
        ATTN_TILE(t,     0, bvA, bvB)
        ATTN_TILE(t + 1, 1, bvB, bvA)
    }
#undef ATTN_TILE

    // final l reduction (16 lanes per quad-row) + fp32 stores
    float l_loc[4] = {l4[0], l4[1], l4[2], l4[3]};
#pragma unroll
    for (int r = 0; r < 4; ++r) {
#pragma unroll
        for (int d = 1; d < 16; d <<= 1)
            l_loc[r] += __shfl_xor(l_loc[r], d, 64);
        float inv = 1.0f / l_loc[r];
        int qq = q0 + wave * 16 + quad * 4 + r;
#pragma unroll
        for (int tt = 0; tt < 4; ++tt)
            out[((size_t)(b * NN + qq)) * DD + h * HD + tt * 16 + l15] =
                o[tt][r] * inv;
    }
}

// ---------------------------------------------------------------------------
extern "C" void kernel_launch(void* const* d_in, const int* in_sizes, int n_in,
                              void* d_out, int out_size, void* d_ws, size_t ws_size,
                              hipStream_t stream) {
    const float* x      = (const float*)d_in[0];
    const float* coords = (const float*)d_in[1];
    const float* abias  = (const float*)d_in[2];
    const float* Wqkv   = (const float*)d_in[3];
    const float* bqkv   = (const float*)d_in[4];
    const float* relw   = (const float*)d_in[5];
    float* out = (float*)d_out;

    char* ws = (char*)d_ws;
    bf16*  xb  = (bf16*)(ws);                      // 8 MB
    bf16*  qw  = (bf16*)(ws + 8388608);            // 8 MB
    bf16*  kw  = (bf16*)(ws + 16777216);           // 8 MB
    bf16*  vt  = (bf16*)(ws + 25165824);           // 8 MB (bh,d,n) via gemm epilogue
    bf16*  Wt  = (bf16*)(ws + 33554432);           // 6 MB
    float* pbf = (float*)(ws + 39845888);          // 16 MB permuted bias fp32
    bf16*  cpb = (bf16*)(ws + 56623104);           // 128 KB

    prep    <<<dim3(4096),   256, 0, stream>>>(x, abias, Wqkv, coords, relw,
                                               xb, pbf, Wt, cpb);
    qkv_gemm<<<dim3(24, 32), 256, 0, stream>>>(xb, Wt, bqkv, qw, kw, vt);
    attn    <<<dim3(16, 32), 512, 0, stream>>>(qw, kw, vt, cpb, pbf, out);
}